// Round 10
// baseline (291.267 us; speedup 1.0000x reference)
//
#include <hip/hip_runtime.h>

#define LN_EPS 1e-5f
#define D 128
#define SCAN_CHUNK 1024
#define LDSA_STRIDE 264   // bf16 units: 256 + 8 pad; row stride 528B (16B-aligned)
#define AGG_ROWS 32       // 32-row tile: LDS 16.9KB -> 8 blocks/CU (2x occupancy)
#define LNB 1536          // persistent LN blocks (grid-stride)

typedef __attribute__((ext_vector_type(4))) float f32x4;
typedef __attribute__((ext_vector_type(8))) short bf16x8;

static __device__ __forceinline__ ushort f2bf(float f) {
    union { float f; unsigned u; } a; a.f = f;
    unsigned r = a.u + 0x7FFF + ((a.u >> 16) & 1);   // RNE
    return (ushort)(r >> 16);
}
static __device__ __forceinline__ float bf2f(ushort u) {
    union { unsigned u; float f; } a; a.u = ((unsigned)u) << 16;
    return a.f;
}

// K1: three independent roles, NO cross-block sync.
//   [0, LNB):        LN+ReLU+mask -> bf16 h, PERSISTENT grid-stride
//                    (8 nodes/wave/iter; waves loop instead of one-shot).
//   [LNB, LNB+128):  pack B = [Wl^T ; Wr^T] into MFMA B-frag order.
//   rest:            dst-degree histogram, int4, 1 quad/thread.
__global__ void ln_pack_hist(const float* __restrict__ x,
                             const float* __restrict__ mask,
                             const float* __restrict__ gamma,
                             const float* __restrict__ beta,
                             ushort* __restrict__ hbf,
                             const float* __restrict__ Wl,
                             const float* __restrict__ Wr,
                             ushort* __restrict__ Bfrag,
                             const int* __restrict__ ei,
                             int* __restrict__ hist,
                             int N, int E) {
    int bid = (int)blockIdx.x;
    int tid = (int)threadIdx.x;

    if (bid >= LNB + 128) {
        // ---- hist role ----
        int base = ((bid - LNB - 128) * 256 + tid) * 4;
        const int* dst = ei + E;
        if (base + 3 < E) {
            int4 d = *(const int4*)(dst + base);
            atomicAdd(&hist[d.x], 1);
            atomicAdd(&hist[d.y], 1);
            atomicAdd(&hist[d.z], 1);
            atomicAdd(&hist[d.w], 1);
        } else {
            for (int i = base; i < E && i < base + 4; i++)
                atomicAdd(&hist[dst[i]], 1);
        }
        return;
    }
    if (bid >= LNB) {
        // ---- Bfrag-pack role ----
        int t = (bid - LNB) * 256 + tid;   // 0..32767
        int i    = t & 7;
        int lane = (t >> 3) & 63;
        int jb   = (t >> 9) & 7;
        int ks   = t >> 12;
        int k = ks * 32 + (lane >> 4) * 8 + i;
        int j = jb * 16 + (lane & 15);
        float v = (k < D) ? Wl[j * D + k] : Wr[j * D + (k - D)];
        Bfrag[t] = f2bf(v);
        return;
    }

    // ---- LN role: persistent, 8 nodes per wave per iteration ----
    int lane = tid & 63;
    int wid  = bid * 4 + (tid >> 6);
    int nw   = LNB * 4;            // 6144 waves
    int g2   = lane >> 4;          // subgroup 0..3
    int sl   = lane & 15;          // 16 lanes x 8 floats = 128

    f32x4 g0 = *(const f32x4*)(gamma + sl * 8);
    f32x4 g1 = *(const f32x4*)(gamma + sl * 8 + 4);
    f32x4 b0 = *(const f32x4*)(beta + sl * 8);
    f32x4 b1 = *(const f32x4*)(beta + sl * 8 + 4);

    for (int np = wid; np * 8 < N; np += nw) {
        int nodeA = np * 8 + g2;
        int nodeB = nodeA + 4;
        if (nodeA >= N) continue;
        int nB = (nodeB < N) ? nodeB : nodeA;   // clamp loads; store guarded

        const float* xa = x + (size_t)nodeA * D + sl * 8;
        const float* xb = x + (size_t)nB * D + sl * 8;
        const float* ma = mask + (size_t)nodeA * D + sl * 8;
        const float* mb = mask + (size_t)nB * D + sl * 8;
        f32x4 va0 = *(const f32x4*)xa;
        f32x4 va1 = *(const f32x4*)(xa + 4);
        f32x4 vb0 = *(const f32x4*)xb;
        f32x4 vb1 = *(const f32x4*)(xb + 4);
        f32x4 ma0 = *(const f32x4*)ma;
        f32x4 ma1 = *(const f32x4*)(ma + 4);
        f32x4 mb0 = *(const f32x4*)mb;
        f32x4 mb1 = *(const f32x4*)(mb + 4);

        float sA  = (va0.x + va0.y) + (va0.z + va0.w) + (va1.x + va1.y) + (va1.z + va1.w);
        float ssA = (va0.x * va0.x + va0.y * va0.y) + (va0.z * va0.z + va0.w * va0.w)
                  + (va1.x * va1.x + va1.y * va1.y) + (va1.z * va1.z + va1.w * va1.w);
        float sB  = (vb0.x + vb0.y) + (vb0.z + vb0.w) + (vb1.x + vb1.y) + (vb1.z + vb1.w);
        float ssB = (vb0.x * vb0.x + vb0.y * vb0.y) + (vb0.z * vb0.z + vb0.w * vb0.w)
                  + (vb1.x * vb1.x + vb1.y * vb1.y) + (vb1.z * vb1.z + vb1.w * vb1.w);
#pragma unroll
        for (int off = 8; off > 0; off >>= 1) {   // stays within each 16-group
            sA  += __shfl_xor(sA, off);
            ssA += __shfl_xor(ssA, off);
            sB  += __shfl_xor(sB, off);
            ssB += __shfl_xor(ssB, off);
        }
        float muA = sA * (1.0f / D);
        float vrA = ssA * (1.0f / D) - muA * muA;
        float rsA = rsqrtf(vrA + LN_EPS);
        float muB = sB * (1.0f / D);
        float vrB = ssB * (1.0f / D) - muB * muB;
        float rsB = rsqrtf(vrB + LN_EPS);

        bf16x8 oA;
        oA[0] = (short)f2bf(fmaxf((va0.x - muA) * rsA * g0.x + b0.x, 0.0f) * ma0.x);
        oA[1] = (short)f2bf(fmaxf((va0.y - muA) * rsA * g0.y + b0.y, 0.0f) * ma0.y);
        oA[2] = (short)f2bf(fmaxf((va0.z - muA) * rsA * g0.z + b0.z, 0.0f) * ma0.z);
        oA[3] = (short)f2bf(fmaxf((va0.w - muA) * rsA * g0.w + b0.w, 0.0f) * ma0.w);
        oA[4] = (short)f2bf(fmaxf((va1.x - muA) * rsA * g1.x + b1.x, 0.0f) * ma1.x);
        oA[5] = (short)f2bf(fmaxf((va1.y - muA) * rsA * g1.y + b1.y, 0.0f) * ma1.y);
        oA[6] = (short)f2bf(fmaxf((va1.z - muA) * rsA * g1.z + b1.z, 0.0f) * ma1.z);
        oA[7] = (short)f2bf(fmaxf((va1.w - muA) * rsA * g1.w + b1.w, 0.0f) * ma1.w);
        *(bf16x8*)(hbf + (size_t)nodeA * D + sl * 8) = oA;

        if (nodeB < N) {
            bf16x8 oB;
            oB[0] = (short)f2bf(fmaxf((vb0.x - muB) * rsB * g0.x + b0.x, 0.0f) * mb0.x);
            oB[1] = (short)f2bf(fmaxf((vb0.y - muB) * rsB * g0.y + b0.y, 0.0f) * mb0.y);
            oB[2] = (short)f2bf(fmaxf((vb0.z - muB) * rsB * g0.z + b0.z, 0.0f) * mb0.z);
            oB[3] = (short)f2bf(fmaxf((vb0.w - muB) * rsB * g0.w + b0.w, 0.0f) * mb0.w);
            oB[4] = (short)f2bf(fmaxf((vb1.x - muB) * rsB * g1.x + b1.x, 0.0f) * mb1.x);
            oB[5] = (short)f2bf(fmaxf((vb1.y - muB) * rsB * g1.y + b1.y, 0.0f) * mb1.y);
            oB[6] = (short)f2bf(fmaxf((vb1.z - muB) * rsB * g1.z + b1.z, 0.0f) * mb1.z);
            oB[7] = (short)f2bf(fmaxf((vb1.w - muB) * rsB * g1.w + b1.w, 0.0f) * mb1.w);
            *(bf16x8*)(hbf + (size_t)nodeB * D + sl * 8) = oB;
        }
    }
}

// K2: single-pass exclusive scan, 98 blocks (BYTE-IDENTICAL to rounds 2/5/9 —
// proven; every block works first, waits only on lower-numbered blocks).
__global__ void scan_all(const int* __restrict__ hist, int* __restrict__ offs,
                         int* __restrict__ cursor, int* __restrict__ csums, int N) {
    __shared__ int lds[256];
    __shared__ int base_s;
    int base = blockIdx.x * SCAN_CHUNK;
    int t = threadIdx.x;
    int idx0 = base + t * 4;
    int v[4];
#pragma unroll
    for (int i = 0; i < 4; i++) {
        int idx = idx0 + i;
        v[i] = (idx < N) ? hist[idx] : 0;
    }
    lds[t] = v[0] + v[1] + v[2] + v[3];
    __syncthreads();
    for (int off = 1; off < 256; off <<= 1) {
        int add = (t >= off) ? lds[t - off] : 0;
        __syncthreads();
        lds[t] += add;
        __syncthreads();
    }
    int run = (t == 0) ? 0 : lds[t - 1];
    if (t == 255)
        __hip_atomic_store(&csums[blockIdx.x], lds[255] | 0x40000000,
                           __ATOMIC_RELEASE, __HIP_MEMORY_SCOPE_AGENT);
    if (t < 64) {
        int acc = 0;
        for (int c = t; c < (int)blockIdx.x; c += 64) {
            int w;
            do {
                w = __hip_atomic_load(&csums[c], __ATOMIC_ACQUIRE,
                                      __HIP_MEMORY_SCOPE_AGENT);
            } while (!(w & 0x40000000));
            acc += w & 0x3FFFFFFF;
        }
#pragma unroll
        for (int off = 32; off > 0; off >>= 1) acc += __shfl_xor(acc, off);
        if (t == 0) base_s = acc;
    }
    __syncthreads();
    run += base_s;
#pragma unroll
    for (int i = 0; i < 4; i++) {
        int idx = idx0 + i;
        if (idx < N) {
            offs[idx] = run;
            cursor[idx] = run;
        }
        run += v[i];
    }
}

// K3: bucket edges by dst (round-5/9 proven int4 version).
__global__ void sort_edges(const int* __restrict__ ei, int* __restrict__ cursor,
                           int* __restrict__ sorted_src, int E) {
    int base = (blockIdx.x * blockDim.x + threadIdx.x) * 4;
    if (base >= E) return;
    if (base + 3 < E) {
        int4 d = *(const int4*)(ei + E + base);
        int4 s = *(const int4*)(ei + base);
        int p0 = atomicAdd(&cursor[d.x], 1);
        int p1 = atomicAdd(&cursor[d.y], 1);
        int p2 = atomicAdd(&cursor[d.z], 1);
        int p3 = atomicAdd(&cursor[d.w], 1);
        sorted_src[p0] = s.x;
        sorted_src[p1] = s.y;
        sorted_src[p2] = s.z;
        sorted_src[p3] = s.w;
    } else {
        for (int e = base; e < E; e++) {
            int pos = atomicAdd(&cursor[ei[E + e]], 1);
            sorted_src[pos] = ei[e];
        }
    }
}

// K4: 32-ROW tile (LDS 16.9KB -> 8 blocks/CU, 2x the 64-row version's
// occupancy cap; gather is latency-bound at 29% occupancy). Per 16-lane
// subgroup: 2 rows x 4-deep pipeline = 8 gathers in flight (same proven
// footprint as 4 rows x 2-deep; 16-deep thrashed L2 in round 4).
// LDS epilogue (round-9): stage f32 tile, full-line stores (kills out-RFO).
__global__ void __launch_bounds__(256, 8)
agg_gemm(float* __restrict__ out,
         const ushort* __restrict__ hbf,
         const int* __restrict__ sorted_src,
         const int* __restrict__ offs,
         const int* __restrict__ hist,
         const ushort* __restrict__ Bfrag,
         const float* __restrict__ bl,
         int N, int E) {
    __shared__ ushort Alds[AGG_ROWS * LDSA_STRIDE];   // 16896 B
    int tid  = threadIdx.x;
    int wave = tid >> 6;
    int lane = tid & 63;
    int n0 = blockIdx.x * AGG_ROWS;

    // stage h rows (coalesced) into Alds[row][128..255]
#pragma unroll
    for (int it = 0; it < 2; it++) {
        int chunk = tid + 256 * it;          // 0..511: 32 rows x 16 chunks
        int row = chunk >> 4;
        int c8  = chunk & 15;
        int node = n0 + row;
        bf16x8 vh = (bf16x8){0,0,0,0,0,0,0,0};
        if (node < N) vh = *(const bf16x8*)(hbf + (size_t)node * D + c8 * 8);
        *(bf16x8*)&Alds[row * LDSA_STRIDE + 128 + c8 * 8] = vh;
    }

    // aggregate 32 rows into Alds[row][0..127]; subgroup owns rows row0, row0+4
    int g  = lane >> 4;
    int sl = lane & 15;
    int row0 = wave * 8 + g;
    int start[2], deg[2], dm1[2];
#pragma unroll
    for (int p = 0; p < 2; p++) {
        int node = n0 + row0 + p * 4;
        start[p] = 0; deg[p] = 0;
        if (node < N) { start[p] = offs[node]; deg[p] = hist[node]; }
        dm1[p] = deg[p] - 1; if (dm1[p] < 0) dm1[p] = 0;
    }
    float acc[2][8];
#pragma unroll
    for (int p = 0; p < 2; p++)
#pragma unroll
        for (int q = 0; q < 8; q++) acc[p][q] = 0.0f;

    int dmax = max(deg[0], deg[1]);
    int Em = E - 1;
    int idx[4][2];                 // idx[k][p] = src for edge j+k of row p
#pragma unroll
    for (int k = 0; k < 4; k++)
#pragma unroll
        for (int p = 0; p < 2; p++) {
            int jc = (k < dm1[p]) ? k : dm1[p];
            int pos = start[p] + jc; if (pos > Em) pos = Em;
            idx[k][p] = sorted_src[pos];
        }
    for (int j = 0; j < dmax; j += 4) {
        int cur[4][2];
#pragma unroll
        for (int k = 0; k < 4; k++)
#pragma unroll
            for (int p = 0; p < 2; p++) cur[k][p] = idx[k][p];
        // prefetch indices for j+4..j+7 (clamped to the row's last edge)
#pragma unroll
        for (int k = 0; k < 4; k++)
#pragma unroll
            for (int p = 0; p < 2; p++) {
                int jn = j + 4 + k; jn = (jn < dm1[p]) ? jn : dm1[p];
                int pos = start[p] + jn; if (pos > Em) pos = Em;
                idx[k][p] = sorted_src[pos];
            }
        // 8 independent row gathers (2 rows x 4 edges)
#pragma unroll
        for (int k = 0; k < 4; k++) {
#pragma unroll
            for (int p = 0; p < 2; p++) {
                bf16x8 v = *(const bf16x8*)(hbf + (size_t)cur[k][p] * D + sl * 8);
                float m = (j + k < deg[p]) ? 1.0f : 0.0f;
#pragma unroll
                for (int q = 0; q < 8; q++) acc[p][q] += bf2f((ushort)v[q]) * m;
            }
        }
    }
#pragma unroll
    for (int p = 0; p < 2; p++) {
        float inv = 1.0f / fmaxf((float)deg[p], 1.0f);
        bf16x8 o;
#pragma unroll
        for (int q = 0; q < 8; q++) o[q] = (short)f2bf(acc[p][q] * inv);
        *(bf16x8*)&Alds[(row0 + p * 4) * LDSA_STRIDE + sl * 8] = o;
    }
    __syncthreads();

    // MFMA: [magg | h] @ B + bias (breg loaded post-gather)
    bf16x8 breg[8][2];
#pragma unroll
    for (int ks = 0; ks < 8; ks++)
#pragma unroll
        for (int jj = 0; jj < 2; jj++) {
            int jb = wave * 2 + jj;
            breg[ks][jj] = *(const bf16x8*)(Bfrag + (size_t)((ks * 8 + jb) * 64 + lane) * 8);
        }

    f32x4 acc2[2][2];
#pragma unroll
    for (int nb = 0; nb < 2; nb++)
#pragma unroll
        for (int jj = 0; jj < 2; jj++)
            acc2[nb][jj] = (f32x4){0.f, 0.f, 0.f, 0.f};

    int arow = lane & 15;
    int akoff = (lane >> 4) * 8;
#pragma unroll
    for (int ks = 0; ks < 8; ks++) {
#pragma unroll
        for (int nb = 0; nb < 2; nb++) {
            bf16x8 a = *(const bf16x8*)&Alds[(nb * 16 + arow) * LDSA_STRIDE + ks * 32 + akoff];
            acc2[nb][0] = __builtin_amdgcn_mfma_f32_16x16x32_bf16(a, breg[ks][0], acc2[nb][0], 0, 0, 0);
            acc2[nb][1] = __builtin_amdgcn_mfma_f32_16x16x32_bf16(a, breg[ks][1], acc2[nb][1], 0, 0, 0);
        }
    }

    // epilogue: stage f32 tile in LDS, then coalesced full-line stores
    __syncthreads();                         // all MFMA reads of Alds done
    float* fl = (float*)Alds;                // 32*128*4B = 16384 <= 16896
    float bias0 = bl[wave * 32 + (lane & 15)];
    float bias1 = bl[wave * 32 + 16 + (lane & 15)];
    int rbase = (lane >> 4) * 4;
    int c0 = wave * 32 + (lane & 15);
#pragma unroll
    for (int nb = 0; nb < 2; nb++) {
#pragma unroll
        for (int r = 0; r < 4; r++) {
            int row = nb * 16 + rbase + r;
            fl[row * 128 + c0]      = acc2[nb][0][r] + bias0;
            fl[row * 128 + c0 + 16] = acc2[nb][1][r] + bias1;
        }
    }
    __syncthreads();
#pragma unroll
    for (int it = 0; it < 4; it++) {
        int c = tid + it * 256;              // 1024 chunks = 32 rows x 32
        int row = c >> 5;
        int q   = c & 31;
        if (n0 + row < N)
            *(f32x4*)(out + (size_t)(n0 + row) * D + q * 4) =
                *(const f32x4*)&fl[row * 128 + q * 4];
    }
}

extern "C" void kernel_launch(void* const* d_in, const int* in_sizes, int n_in,
                              void* d_out, int out_size, void* d_ws, size_t ws_size,
                              hipStream_t stream) {
    const float* x     = (const float*)d_in[0];
    const int*   ei    = (const int*)  d_in[1];
    const float* mask  = (const float*)d_in[2];
    const float* gamma = (const float*)d_in[3];
    const float* beta  = (const float*)d_in[4];
    const float* Wl    = (const float*)d_in[5];
    const float* bl    = (const float*)d_in[6];
    const float* Wr    = (const float*)d_in[7];
    float* out = (float*)d_out;

    int N = in_sizes[0] / D;   // 100000
    int E = in_sizes[1] / 2;   // 600000
    int chunks = (N + SCAN_CHUNK - 1) / SCAN_CHUNK;  // 98

    // ws layout: hbf[N*D] us | Bfrag[32768] us | hist[N] | csums[128] |
    //            offs[N] | cursor[N] | sorted_src[E]
    ushort* hbf   = (ushort*)d_ws;
    ushort* Bfrag = hbf + (size_t)N * D;
    int* hist   = (int*)(Bfrag + 32768);
    int* csums  = hist + N;
    int* offs   = csums + 128;
    int* cursor = offs + N;
    int* ssrc   = cursor + N;

    int histBlocks = (E + 1023) / 1024;    // 586

    hipMemsetAsync(hist, 0, (size_t)(N + 128) * sizeof(int), stream);
    ln_pack_hist<<<LNB + 128 + histBlocks, 256, 0, stream>>>(
        x, mask, gamma, beta, hbf, Wl, Wr, Bfrag, ei, hist, N, E);
    scan_all<<<chunks, 256, 0, stream>>>(hist, offs, cursor, csums, N);
    sort_edges<<<(E / 4 + 255) / 256, 256, 0, stream>>>(ei, cursor, ssrc, E);
    agg_gemm<<<(N + AGG_ROWS - 1) / AGG_ROWS, 256, 0, stream>>>(
        out, hbf, ssrc, offs, hist, Bfrag, bl, N, E);
}

// Round 11
// 256.421 us; speedup vs baseline: 1.1359x; 1.1359x over previous
//
#include <hip/hip_runtime.h>

#define LN_EPS 1e-5f
#define D 128
#define SCAN_CHUNK 1024
#define LDSA_STRIDE 264   // bf16 units: 256 + 8 pad; row stride 528B (16B-aligned)

typedef __attribute__((ext_vector_type(4))) float f32x4;
typedef __attribute__((ext_vector_type(8))) short bf16x8;

static __device__ __forceinline__ ushort f2bf(float f) {
    union { float f; unsigned u; } a; a.f = f;
    unsigned r = a.u + 0x7FFF + ((a.u >> 16) & 1);   // RNE
    return (ushort)(r >> 16);
}
static __device__ __forceinline__ float bf2f(ushort u) {
    union { unsigned u; float f; } a; a.u = ((unsigned)u) << 16;
    return a.f;
}

// K1: three independent roles, NO cross-block sync.
//   [0, lnBlocks):   LN+ReLU+mask -> bf16 h. 32 lanes/node (one f32x4 per
//                    lane per array = single-instruction full-row coverage),
//                    2 nodes/wave, nontemporal x/mask loads (zero reuse).
//   next 128:        pack B = [Wl^T ; Wr^T] into MFMA B-frag order.
//   rest:            dst-degree histogram, int4, 1 quad/thread.
__global__ void ln_pack_hist(const float* __restrict__ x,
                             const float* __restrict__ mask,
                             const float* __restrict__ gamma,
                             const float* __restrict__ beta,
                             ushort* __restrict__ hbf,
                             const float* __restrict__ Wl,
                             const float* __restrict__ Wr,
                             ushort* __restrict__ Bfrag,
                             const int* __restrict__ ei,
                             int* __restrict__ hist,
                             int N, int E, int lnBlocks) {
    int bid = (int)blockIdx.x;
    int tid = (int)threadIdx.x;

    if (bid >= lnBlocks + 128) {
        // ---- hist role ----
        int base = ((bid - lnBlocks - 128) * 256 + tid) * 4;
        const int* dst = ei + E;
        if (base + 3 < E) {
            int4 d = *(const int4*)(dst + base);
            atomicAdd(&hist[d.x], 1);
            atomicAdd(&hist[d.y], 1);
            atomicAdd(&hist[d.z], 1);
            atomicAdd(&hist[d.w], 1);
        } else {
            for (int i = base; i < E && i < base + 4; i++)
                atomicAdd(&hist[dst[i]], 1);
        }
        return;
    }
    if (bid >= lnBlocks) {
        // ---- Bfrag-pack role ----
        int t = (bid - lnBlocks) * 256 + tid;   // 0..32767
        int i    = t & 7;
        int lane = (t >> 3) & 63;
        int jb   = (t >> 9) & 7;
        int ks   = t >> 12;
        int k = ks * 32 + (lane >> 4) * 8 + i;
        int j = jb * 16 + (lane & 15);
        float v = (k < D) ? Wl[j * D + k] : Wr[j * D + (k - D)];
        Bfrag[t] = f2bf(v);
        return;
    }

    // ---- LN role: 2 nodes/wave, 32 lanes/node ----
    int lane = tid & 63;
    int wid  = bid * 4 + (tid >> 6);
    int half = lane >> 5;          // node within wave
    int sl   = lane & 31;          // 32 lanes x f32x4 = 128 floats
    int node = wid * 2 + half;
    if (node >= N) return;

    f32x4 v = __builtin_nontemporal_load((const f32x4*)(x + (size_t)node * D) + sl);
    f32x4 m = __builtin_nontemporal_load((const f32x4*)(mask + (size_t)node * D) + sl);

    float s  = (v.x + v.y) + (v.z + v.w);
    float ss = (v.x * v.x + v.y * v.y) + (v.z * v.z + v.w * v.w);
#pragma unroll
    for (int off = 16; off > 0; off >>= 1) {   // xor<32 stays within each node
        s  += __shfl_xor(s, off);
        ss += __shfl_xor(ss, off);
    }
    float mu  = s * (1.0f / D);
    float var = ss * (1.0f / D) - mu * mu;
    float rs  = rsqrtf(var + LN_EPS);

    f32x4 g = ((const f32x4*)gamma)[sl];
    f32x4 b = ((const f32x4*)beta)[sl];

    ushort4 o;
    o.x = f2bf(fmaxf((v.x - mu) * rs * g.x + b.x, 0.0f) * m.x);
    o.y = f2bf(fmaxf((v.y - mu) * rs * g.y + b.y, 0.0f) * m.y);
    o.z = f2bf(fmaxf((v.z - mu) * rs * g.z + b.z, 0.0f) * m.z);
    o.w = f2bf(fmaxf((v.w - mu) * rs * g.w + b.w, 0.0f) * m.w);
    ((ushort4*)(hbf + (size_t)node * D))[sl] = o;
}

// K2: single-pass exclusive scan, 98 blocks (BYTE-IDENTICAL to rounds 2/5/9 —
// proven; every block works first, waits only on lower-numbered blocks).
__global__ void scan_all(const int* __restrict__ hist, int* __restrict__ offs,
                         int* __restrict__ cursor, int* __restrict__ csums, int N) {
    __shared__ int lds[256];
    __shared__ int base_s;
    int base = blockIdx.x * SCAN_CHUNK;
    int t = threadIdx.x;
    int idx0 = base + t * 4;
    int v[4];
#pragma unroll
    for (int i = 0; i < 4; i++) {
        int idx = idx0 + i;
        v[i] = (idx < N) ? hist[idx] : 0;
    }
    lds[t] = v[0] + v[1] + v[2] + v[3];
    __syncthreads();
    for (int off = 1; off < 256; off <<= 1) {
        int add = (t >= off) ? lds[t - off] : 0;
        __syncthreads();
        lds[t] += add;
        __syncthreads();
    }
    int run = (t == 0) ? 0 : lds[t - 1];
    if (t == 255)
        __hip_atomic_store(&csums[blockIdx.x], lds[255] | 0x40000000,
                           __ATOMIC_RELEASE, __HIP_MEMORY_SCOPE_AGENT);
    if (t < 64) {
        int acc = 0;
        for (int c = t; c < (int)blockIdx.x; c += 64) {
            int w;
            do {
                w = __hip_atomic_load(&csums[c], __ATOMIC_ACQUIRE,
                                      __HIP_MEMORY_SCOPE_AGENT);
            } while (!(w & 0x40000000));
            acc += w & 0x3FFFFFFF;
        }
#pragma unroll
        for (int off = 32; off > 0; off >>= 1) acc += __shfl_xor(acc, off);
        if (t == 0) base_s = acc;
    }
    __syncthreads();
    run += base_s;
#pragma unroll
    for (int i = 0; i < 4; i++) {
        int idx = idx0 + i;
        if (idx < N) {
            offs[idx] = run;
            cursor[idx] = run;
        }
        run += v[i];
    }
}

// K3: bucket edges by dst (round-5/9 proven int4 version).
__global__ void sort_edges(const int* __restrict__ ei, int* __restrict__ cursor,
                           int* __restrict__ sorted_src, int E) {
    int base = (blockIdx.x * blockDim.x + threadIdx.x) * 4;
    if (base >= E) return;
    if (base + 3 < E) {
        int4 d = *(const int4*)(ei + E + base);
        int4 s = *(const int4*)(ei + base);
        int p0 = atomicAdd(&cursor[d.x], 1);
        int p1 = atomicAdd(&cursor[d.y], 1);
        int p2 = atomicAdd(&cursor[d.z], 1);
        int p3 = atomicAdd(&cursor[d.w], 1);
        sorted_src[p0] = s.x;
        sorted_src[p1] = s.y;
        sorted_src[p2] = s.z;
        sorted_src[p3] = s.w;
    } else {
        for (int e = base; e < E; e++) {
            int pos = atomicAdd(&cursor[ei[E + e]], 1);
            sorted_src[pos] = ei[e];
        }
    }
}

// K4: BYTE-IDENTICAL to round 9 (proven): 64-row tile, 4 blocks/CU, x2-unroll
// gather (8 in flight/subgroup — the L2-sustainable ceiling; x4 unroll AND
// 8-blocks/CU both thrash L2, rounds 4/10), LDS epilogue full-line stores.
__global__ void __launch_bounds__(256, 4)
agg_gemm(float* __restrict__ out,
         const ushort* __restrict__ hbf,
         const int* __restrict__ sorted_src,
         const int* __restrict__ offs,
         const int* __restrict__ hist,
         const ushort* __restrict__ Bfrag,
         const float* __restrict__ bl,
         int N, int E) {
    __shared__ ushort Alds[64 * LDSA_STRIDE];
    int tid  = threadIdx.x;
    int wave = tid >> 6;
    int lane = tid & 63;
    int n0 = blockIdx.x * 64;

#pragma unroll
    for (int it = 0; it < 4; it++) {
        int chunk = tid + 256 * it;
        int row = chunk >> 4;
        int c8  = chunk & 15;
        int node = n0 + row;
        bf16x8 vh = (bf16x8){0,0,0,0,0,0,0,0};
        if (node < N) vh = *(const bf16x8*)(hbf + (size_t)node * D + c8 * 8);
        *(bf16x8*)&Alds[row * LDSA_STRIDE + 128 + c8 * 8] = vh;
    }

    int g  = lane >> 4;
    int sl = lane & 15;
    int row0 = wave * 16 + g;
    int start[4], deg[4], dm1[4];
#pragma unroll
    for (int p = 0; p < 4; p++) {
        int node = n0 + row0 + p * 4;
        start[p] = 0; deg[p] = 0;
        if (node < N) { start[p] = offs[node]; deg[p] = hist[node]; }
        dm1[p] = deg[p] - 1; if (dm1[p] < 0) dm1[p] = 0;
    }
    float acc[4][8];
#pragma unroll
    for (int p = 0; p < 4; p++)
#pragma unroll
        for (int q = 0; q < 8; q++) acc[p][q] = 0.0f;

    int dmax = max(max(deg[0], deg[1]), max(deg[2], deg[3]));
    int Em = E - 1;
    int ia[4], ib[4];
#pragma unroll
    for (int p = 0; p < 4; p++) {
        int pa = start[p];                         if (pa > Em) pa = Em;
        int j1 = (1 < dm1[p]) ? 1 : dm1[p];
        int pb = start[p] + j1;                    if (pb > Em) pb = Em;
        ia[p] = sorted_src[pa];
        ib[p] = sorted_src[pb];
    }
    for (int j = 0; j < dmax; j += 2) {
        int ca[4], cb[4];
#pragma unroll
        for (int p = 0; p < 4; p++) { ca[p] = ia[p]; cb[p] = ib[p]; }
#pragma unroll
        for (int p = 0; p < 4; p++) {
            int j2 = (j + 2 < dm1[p]) ? j + 2 : dm1[p];
            int j3 = (j + 3 < dm1[p]) ? j + 3 : dm1[p];
            int pa = start[p] + j2; if (pa > Em) pa = Em;
            int pb = start[p] + j3; if (pb > Em) pb = Em;
            ia[p] = sorted_src[pa];
            ib[p] = sorted_src[pb];
        }
#pragma unroll
        for (int p = 0; p < 4; p++) {
            bf16x8 v = *(const bf16x8*)(hbf + (size_t)ca[p] * D + sl * 8);
            float m = (j < deg[p]) ? 1.0f : 0.0f;
#pragma unroll
            for (int q = 0; q < 8; q++) acc[p][q] += bf2f((ushort)v[q]) * m;
        }
#pragma unroll
        for (int p = 0; p < 4; p++) {
            bf16x8 v = *(const bf16x8*)(hbf + (size_t)cb[p] * D + sl * 8);
            float m = (j + 1 < deg[p]) ? 1.0f : 0.0f;
#pragma unroll
            for (int q = 0; q < 8; q++) acc[p][q] += bf2f((ushort)v[q]) * m;
        }
    }
#pragma unroll
    for (int p = 0; p < 4; p++) {
        float inv = 1.0f / fmaxf((float)deg[p], 1.0f);
        bf16x8 o;
#pragma unroll
        for (int q = 0; q < 8; q++) o[q] = (short)f2bf(acc[p][q] * inv);
        *(bf16x8*)&Alds[(row0 + p * 4) * LDSA_STRIDE + sl * 8] = o;
    }
    __syncthreads();

    bf16x8 breg[8][2];
#pragma unroll
    for (int ks = 0; ks < 8; ks++)
#pragma unroll
        for (int jj = 0; jj < 2; jj++) {
            int jb = wave * 2 + jj;
            breg[ks][jj] = *(const bf16x8*)(Bfrag + (size_t)((ks * 8 + jb) * 64 + lane) * 8);
        }

    f32x4 acc2[4][2];
#pragma unroll
    for (int nb = 0; nb < 4; nb++)
#pragma unroll
        for (int jj = 0; jj < 2; jj++)
            acc2[nb][jj] = (f32x4){0.f, 0.f, 0.f, 0.f};

    int arow = lane & 15;
    int akoff = (lane >> 4) * 8;
#pragma unroll
    for (int ks = 0; ks < 8; ks++) {
#pragma unroll
        for (int nb = 0; nb < 4; nb++) {
            bf16x8 a = *(const bf16x8*)&Alds[(nb * 16 + arow) * LDSA_STRIDE + ks * 32 + akoff];
            acc2[nb][0] = __builtin_amdgcn_mfma_f32_16x16x32_bf16(a, breg[ks][0], acc2[nb][0], 0, 0, 0);
            acc2[nb][1] = __builtin_amdgcn_mfma_f32_16x16x32_bf16(a, breg[ks][1], acc2[nb][1], 0, 0, 0);
        }
    }

    // epilogue: stage f32 tile in LDS, then coalesced full-line stores
    __syncthreads();                         // all MFMA reads of Alds done
    float* fl = (float*)Alds;                // 64*128*4B = 32768B <= 33792B
    float bias0 = bl[wave * 32 + (lane & 15)];
    float bias1 = bl[wave * 32 + 16 + (lane & 15)];
    int rbase = (lane >> 4) * 4;
    int c0 = wave * 32 + (lane & 15);
#pragma unroll
    for (int nb = 0; nb < 4; nb++) {
#pragma unroll
        for (int r = 0; r < 4; r++) {
            int row = nb * 16 + rbase + r;
            fl[row * 128 + c0]      = acc2[nb][0][r] + bias0;
            fl[row * 128 + c0 + 16] = acc2[nb][1][r] + bias1;
        }
    }
    __syncthreads();
#pragma unroll
    for (int it = 0; it < 8; it++) {
        int c = tid + it * 256;              // 2048 chunks = 64 rows x 32
        int row = c >> 5;
        int q   = c & 31;
        if (n0 + row < N)
            *(f32x4*)(out + (size_t)(n0 + row) * D + q * 4) =
                *(const f32x4*)&fl[row * 128 + q * 4];
    }
}

extern "C" void kernel_launch(void* const* d_in, const int* in_sizes, int n_in,
                              void* d_out, int out_size, void* d_ws, size_t ws_size,
                              hipStream_t stream) {
    const float* x     = (const float*)d_in[0];
    const int*   ei    = (const int*)  d_in[1];
    const float* mask  = (const float*)d_in[2];
    const float* gamma = (const float*)d_in[3];
    const float* beta  = (const float*)d_in[4];
    const float* Wl    = (const float*)d_in[5];
    const float* bl    = (const float*)d_in[6];
    const float* Wr    = (const float*)d_in[7];
    float* out = (float*)d_out;

    int N = in_sizes[0] / D;   // 100000
    int E = in_sizes[1] / 2;   // 600000
    int chunks = (N + SCAN_CHUNK - 1) / SCAN_CHUNK;  // 98

    // ws layout: hbf[N*D] us | Bfrag[32768] us | hist[N] | csums[128] |
    //            offs[N] | cursor[N] | sorted_src[E]
    ushort* hbf   = (ushort*)d_ws;
    ushort* Bfrag = hbf + (size_t)N * D;
    int* hist   = (int*)(Bfrag + 32768);
    int* csums  = hist + N;
    int* offs   = csums + 128;
    int* cursor = offs + N;
    int* ssrc   = cursor + N;

    int lnBlocks   = (N + 7) / 8;          // 12500: 4 waves x 2 nodes per block
    int histBlocks = (E + 1023) / 1024;    // 586

    hipMemsetAsync(hist, 0, (size_t)(N + 128) * sizeof(int), stream);
    ln_pack_hist<<<lnBlocks + 128 + histBlocks, 256, 0, stream>>>(
        x, mask, gamma, beta, hbf, Wl, Wr, Bfrag, ei, hist, N, E, lnBlocks);
    scan_all<<<chunks, 256, 0, stream>>>(hist, offs, cursor, csums, N);
    sort_edges<<<(E / 4 + 255) / 256, 256, 0, stream>>>(ei, cursor, ssrc, E);
    agg_gemm<<<(N + 63) / 64, 256, 0, stream>>>(out, hbf, ssrc, offs, hist,
                                                Bfrag, bl, N, E);
}

// Round 12
// 253.007 us; speedup vs baseline: 1.1512x; 1.0135x over previous
//
#include <hip/hip_runtime.h>

#define LN_EPS 1e-5f
#define D 128
#define SCAN_CHUNK 1024
#define LDSA_STRIDE 264   // bf16 units: 256 + 8 pad; row stride 528B (16B-aligned)

typedef __attribute__((ext_vector_type(4))) float f32x4;
typedef __attribute__((ext_vector_type(8))) short bf16x8;

static __device__ __forceinline__ ushort f2bf(float f) {
    union { float f; unsigned u; } a; a.f = f;
    unsigned r = a.u + 0x7FFF + ((a.u >> 16) & 1);   // RNE
    return (ushort)(r >> 16);
}
static __device__ __forceinline__ float bf2f(ushort u) {
    union { unsigned u; float f; } a; a.u = ((unsigned)u) << 16;
    return a.f;
}

// K1: three independent roles, NO cross-block sync (round-11 proven).
//   [0, lnBlocks):   LN+ReLU+mask -> bf16 h. 32 lanes/node, 2 nodes/wave,
//                    nontemporal x/mask loads (zero reuse).
//   next 128:        pack B = [Wl^T ; Wr^T] into MFMA B-frag order.
//   rest:            dst-degree histogram, int4, 1 quad/thread.
__global__ void ln_pack_hist(const float* __restrict__ x,
                             const float* __restrict__ mask,
                             const float* __restrict__ gamma,
                             const float* __restrict__ beta,
                             ushort* __restrict__ hbf,
                             const float* __restrict__ Wl,
                             const float* __restrict__ Wr,
                             ushort* __restrict__ Bfrag,
                             const int* __restrict__ ei,
                             int* __restrict__ hist,
                             int N, int E, int lnBlocks) {
    int bid = (int)blockIdx.x;
    int tid = (int)threadIdx.x;

    if (bid >= lnBlocks + 128) {
        // ---- hist role ----
        int base = ((bid - lnBlocks - 128) * 256 + tid) * 4;
        const int* dst = ei + E;
        if (base + 3 < E) {
            int4 d = *(const int4*)(dst + base);
            atomicAdd(&hist[d.x], 1);
            atomicAdd(&hist[d.y], 1);
            atomicAdd(&hist[d.z], 1);
            atomicAdd(&hist[d.w], 1);
        } else {
            for (int i = base; i < E && i < base + 4; i++)
                atomicAdd(&hist[dst[i]], 1);
        }
        return;
    }
    if (bid >= lnBlocks) {
        // ---- Bfrag-pack role ----
        int t = (bid - lnBlocks) * 256 + tid;   // 0..32767
        int i    = t & 7;
        int lane = (t >> 3) & 63;
        int jb   = (t >> 9) & 7;
        int ks   = t >> 12;
        int k = ks * 32 + (lane >> 4) * 8 + i;
        int j = jb * 16 + (lane & 15);
        float v = (k < D) ? Wl[j * D + k] : Wr[j * D + (k - D)];
        Bfrag[t] = f2bf(v);
        return;
    }

    // ---- LN role: 2 nodes/wave, 32 lanes/node ----
    int lane = tid & 63;
    int wid  = bid * 4 + (tid >> 6);
    int half = lane >> 5;          // node within wave
    int sl   = lane & 31;          // 32 lanes x f32x4 = 128 floats
    int node = wid * 2 + half;
    if (node >= N) return;

    f32x4 v = __builtin_nontemporal_load((const f32x4*)(x + (size_t)node * D) + sl);
    f32x4 m = __builtin_nontemporal_load((const f32x4*)(mask + (size_t)node * D) + sl);

    float s  = (v.x + v.y) + (v.z + v.w);
    float ss = (v.x * v.x + v.y * v.y) + (v.z * v.z + v.w * v.w);
#pragma unroll
    for (int off = 16; off > 0; off >>= 1) {   // xor<32 stays within each node
        s  += __shfl_xor(s, off);
        ss += __shfl_xor(ss, off);
    }
    float mu  = s * (1.0f / D);
    float var = ss * (1.0f / D) - mu * mu;
    float rs  = rsqrtf(var + LN_EPS);

    f32x4 g = ((const f32x4*)gamma)[sl];
    f32x4 b = ((const f32x4*)beta)[sl];

    ushort4 o;
    o.x = f2bf(fmaxf((v.x - mu) * rs * g.x + b.x, 0.0f) * m.x);
    o.y = f2bf(fmaxf((v.y - mu) * rs * g.y + b.y, 0.0f) * m.y);
    o.z = f2bf(fmaxf((v.z - mu) * rs * g.z + b.z, 0.0f) * m.z);
    o.w = f2bf(fmaxf((v.w - mu) * rs * g.w + b.w, 0.0f) * m.w);
    ((ushort4*)(hbf + (size_t)node * D))[sl] = o;
}

// K2: single-pass exclusive scan, 98 blocks (BYTE-IDENTICAL, proven 4x).
__global__ void scan_all(const int* __restrict__ hist, int* __restrict__ offs,
                         int* __restrict__ cursor, int* __restrict__ csums, int N) {
    __shared__ int lds[256];
    __shared__ int base_s;
    int base = blockIdx.x * SCAN_CHUNK;
    int t = threadIdx.x;
    int idx0 = base + t * 4;
    int v[4];
#pragma unroll
    for (int i = 0; i < 4; i++) {
        int idx = idx0 + i;
        v[i] = (idx < N) ? hist[idx] : 0;
    }
    lds[t] = v[0] + v[1] + v[2] + v[3];
    __syncthreads();
    for (int off = 1; off < 256; off <<= 1) {
        int add = (t >= off) ? lds[t - off] : 0;
        __syncthreads();
        lds[t] += add;
        __syncthreads();
    }
    int run = (t == 0) ? 0 : lds[t - 1];
    if (t == 255)
        __hip_atomic_store(&csums[blockIdx.x], lds[255] | 0x40000000,
                           __ATOMIC_RELEASE, __HIP_MEMORY_SCOPE_AGENT);
    if (t < 64) {
        int acc = 0;
        for (int c = t; c < (int)blockIdx.x; c += 64) {
            int w;
            do {
                w = __hip_atomic_load(&csums[c], __ATOMIC_ACQUIRE,
                                      __HIP_MEMORY_SCOPE_AGENT);
            } while (!(w & 0x40000000));
            acc += w & 0x3FFFFFFF;
        }
#pragma unroll
        for (int off = 32; off > 0; off >>= 1) acc += __shfl_xor(acc, off);
        if (t == 0) base_s = acc;
    }
    __syncthreads();
    run += base_s;
#pragma unroll
    for (int i = 0; i < 4; i++) {
        int idx = idx0 + i;
        if (idx < N) {
            offs[idx] = run;
            cursor[idx] = run;
        }
        run += v[i];
    }
}

// K3: bucket edges by dst (proven int4 version).
__global__ void sort_edges(const int* __restrict__ ei, int* __restrict__ cursor,
                           int* __restrict__ sorted_src, int E) {
    int base = (blockIdx.x * blockDim.x + threadIdx.x) * 4;
    if (base >= E) return;
    if (base + 3 < E) {
        int4 d = *(const int4*)(ei + E + base);
        int4 s = *(const int4*)(ei + base);
        int p0 = atomicAdd(&cursor[d.x], 1);
        int p1 = atomicAdd(&cursor[d.y], 1);
        int p2 = atomicAdd(&cursor[d.z], 1);
        int p3 = atomicAdd(&cursor[d.w], 1);
        sorted_src[p0] = s.x;
        sorted_src[p1] = s.y;
        sorted_src[p2] = s.z;
        sorted_src[p3] = s.w;
    } else {
        for (int e = base; e < E; e++) {
            int pos = atomicAdd(&cursor[ei[E + e]], 1);
            sorted_src[pos] = ei[e];
        }
    }
}

// K4: round-9/11 proven structure (64-row tile, 4 blocks/CU, x2-unroll gather
// = the L2-sustainable concurrency; x4 unroll AND 8 blocks/CU both thrash L2)
// + ONE change: NONTEMPORAL stores for `out` (never re-read). The 51MB of
// out-writes were streaming through per-XCD L2 (write-allocate), evicting the
// gather's hbf lines — the ~51MB gather re-fetch component of FETCH_SIZE.
__global__ void __launch_bounds__(256, 4)
agg_gemm(float* __restrict__ out,
         const ushort* __restrict__ hbf,
         const int* __restrict__ sorted_src,
         const int* __restrict__ offs,
         const int* __restrict__ hist,
         const ushort* __restrict__ Bfrag,
         const float* __restrict__ bl,
         int N, int E) {
    __shared__ ushort Alds[64 * LDSA_STRIDE];
    int tid  = threadIdx.x;
    int wave = tid >> 6;
    int lane = tid & 63;
    int n0 = blockIdx.x * 64;

#pragma unroll
    for (int it = 0; it < 4; it++) {
        int chunk = tid + 256 * it;
        int row = chunk >> 4;
        int c8  = chunk & 15;
        int node = n0 + row;
        bf16x8 vh = (bf16x8){0,0,0,0,0,0,0,0};
        if (node < N) vh = *(const bf16x8*)(hbf + (size_t)node * D + c8 * 8);
        *(bf16x8*)&Alds[row * LDSA_STRIDE + 128 + c8 * 8] = vh;
    }

    int g  = lane >> 4;
    int sl = lane & 15;
    int row0 = wave * 16 + g;
    int start[4], deg[4], dm1[4];
#pragma unroll
    for (int p = 0; p < 4; p++) {
        int node = n0 + row0 + p * 4;
        start[p] = 0; deg[p] = 0;
        if (node < N) { start[p] = offs[node]; deg[p] = hist[node]; }
        dm1[p] = deg[p] - 1; if (dm1[p] < 0) dm1[p] = 0;
    }
    float acc[4][8];
#pragma unroll
    for (int p = 0; p < 4; p++)
#pragma unroll
        for (int q = 0; q < 8; q++) acc[p][q] = 0.0f;

    int dmax = max(max(deg[0], deg[1]), max(deg[2], deg[3]));
    int Em = E - 1;
    int ia[4], ib[4];
#pragma unroll
    for (int p = 0; p < 4; p++) {
        int pa = start[p];                         if (pa > Em) pa = Em;
        int j1 = (1 < dm1[p]) ? 1 : dm1[p];
        int pb = start[p] + j1;                    if (pb > Em) pb = Em;
        ia[p] = sorted_src[pa];
        ib[p] = sorted_src[pb];
    }
    for (int j = 0; j < dmax; j += 2) {
        int ca[4], cb[4];
#pragma unroll
        for (int p = 0; p < 4; p++) { ca[p] = ia[p]; cb[p] = ib[p]; }
#pragma unroll
        for (int p = 0; p < 4; p++) {
            int j2 = (j + 2 < dm1[p]) ? j + 2 : dm1[p];
            int j3 = (j + 3 < dm1[p]) ? j + 3 : dm1[p];
            int pa = start[p] + j2; if (pa > Em) pa = Em;
            int pb = start[p] + j3; if (pb > Em) pb = Em;
            ia[p] = sorted_src[pa];
            ib[p] = sorted_src[pb];
        }
#pragma unroll
        for (int p = 0; p < 4; p++) {
            bf16x8 v = *(const bf16x8*)(hbf + (size_t)ca[p] * D + sl * 8);
            float m = (j < deg[p]) ? 1.0f : 0.0f;
#pragma unroll
            for (int q = 0; q < 8; q++) acc[p][q] += bf2f((ushort)v[q]) * m;
        }
#pragma unroll
        for (int p = 0; p < 4; p++) {
            bf16x8 v = *(const bf16x8*)(hbf + (size_t)cb[p] * D + sl * 8);
            float m = (j + 1 < deg[p]) ? 1.0f : 0.0f;
#pragma unroll
            for (int q = 0; q < 8; q++) acc[p][q] += bf2f((ushort)v[q]) * m;
        }
    }
#pragma unroll
    for (int p = 0; p < 4; p++) {
        float inv = 1.0f / fmaxf((float)deg[p], 1.0f);
        bf16x8 o;
#pragma unroll
        for (int q = 0; q < 8; q++) o[q] = (short)f2bf(acc[p][q] * inv);
        *(bf16x8*)&Alds[(row0 + p * 4) * LDSA_STRIDE + sl * 8] = o;
    }
    __syncthreads();

    bf16x8 breg[8][2];
#pragma unroll
    for (int ks = 0; ks < 8; ks++)
#pragma unroll
        for (int jj = 0; jj < 2; jj++) {
            int jb = wave * 2 + jj;
            breg[ks][jj] = *(const bf16x8*)(Bfrag + (size_t)((ks * 8 + jb) * 64 + lane) * 8);
        }

    f32x4 acc2[4][2];
#pragma unroll
    for (int nb = 0; nb < 4; nb++)
#pragma unroll
        for (int jj = 0; jj < 2; jj++)
            acc2[nb][jj] = (f32x4){0.f, 0.f, 0.f, 0.f};

    int arow = lane & 15;
    int akoff = (lane >> 4) * 8;
#pragma unroll
    for (int ks = 0; ks < 8; ks++) {
#pragma unroll
        for (int nb = 0; nb < 4; nb++) {
            bf16x8 a = *(const bf16x8*)&Alds[(nb * 16 + arow) * LDSA_STRIDE + ks * 32 + akoff];
            acc2[nb][0] = __builtin_amdgcn_mfma_f32_16x16x32_bf16(a, breg[ks][0], acc2[nb][0], 0, 0, 0);
            acc2[nb][1] = __builtin_amdgcn_mfma_f32_16x16x32_bf16(a, breg[ks][1], acc2[nb][1], 0, 0, 0);
        }
    }

    // epilogue: stage f32 tile in LDS, then coalesced NONTEMPORAL full-line
    // stores (out is never re-read; keep its 51MB from evicting hbf in L2)
    __syncthreads();                         // all MFMA reads of Alds done
    float* fl = (float*)Alds;                // 64*128*4B = 32768B <= 33792B
    float bias0 = bl[wave * 32 + (lane & 15)];
    float bias1 = bl[wave * 32 + 16 + (lane & 15)];
    int rbase = (lane >> 4) * 4;
    int c0 = wave * 32 + (lane & 15);
#pragma unroll
    for (int nb = 0; nb < 4; nb++) {
#pragma unroll
        for (int r = 0; r < 4; r++) {
            int row = nb * 16 + rbase + r;
            fl[row * 128 + c0]      = acc2[nb][0][r] + bias0;
            fl[row * 128 + c0 + 16] = acc2[nb][1][r] + bias1;
        }
    }
    __syncthreads();
#pragma unroll
    for (int it = 0; it < 8; it++) {
        int c = tid + it * 256;              // 2048 chunks = 64 rows x 32
        int row = c >> 5;
        int q   = c & 31;
        if (n0 + row < N) {
            f32x4 val = *(const f32x4*)&fl[row * 128 + q * 4];
            __builtin_nontemporal_store(
                val, (f32x4*)(out + (size_t)(n0 + row) * D + q * 4));
        }
    }
}

extern "C" void kernel_launch(void* const* d_in, const int* in_sizes, int n_in,
                              void* d_out, int out_size, void* d_ws, size_t ws_size,
                              hipStream_t stream) {
    const float* x     = (const float*)d_in[0];
    const int*   ei    = (const int*)  d_in[1];
    const float* mask  = (const float*)d_in[2];
    const float* gamma = (const float*)d_in[3];
    const float* beta  = (const float*)d_in[4];
    const float* Wl    = (const float*)d_in[5];
    const float* bl    = (const float*)d_in[6];
    const float* Wr    = (const float*)d_in[7];
    float* out = (float*)d_out;

    int N = in_sizes[0] / D;   // 100000
    int E = in_sizes[1] / 2;   // 600000
    int chunks = (N + SCAN_CHUNK - 1) / SCAN_CHUNK;  // 98

    // ws layout: hbf[N*D] us | Bfrag[32768] us | hist[N] | csums[128] |
    //            offs[N] | cursor[N] | sorted_src[E]
    ushort* hbf   = (ushort*)d_ws;
    ushort* Bfrag = hbf + (size_t)N * D;
    int* hist   = (int*)(Bfrag + 32768);
    int* csums  = hist + N;
    int* offs   = csums + 128;
    int* cursor = offs + N;
    int* ssrc   = cursor + N;

    int lnBlocks   = (N + 7) / 8;          // 12500: 4 waves x 2 nodes per block
    int histBlocks = (E + 1023) / 1024;    // 586

    hipMemsetAsync(hist, 0, (size_t)(N + 128) * sizeof(int), stream);
    ln_pack_hist<<<lnBlocks + 128 + histBlocks, 256, 0, stream>>>(
        x, mask, gamma, beta, hbf, Wl, Wr, Bfrag, ei, hist, N, E, lnBlocks);
    scan_all<<<chunks, 256, 0, stream>>>(hist, offs, cursor, csums, N);
    sort_edges<<<(E / 4 + 255) / 256, 256, 0, stream>>>(ei, cursor, ssrc, E);
    agg_gemm<<<(N + 63) / 64, 256, 0, stream>>>(out, hbf, ssrc, offs, hist,
                                                Bfrag, bl, N, E);
}